// Round 9
// baseline (22792.783 us; speedup 1.0000x reference)
//
#include <hip/hip_runtime.h>
#include <stdint.h>

// LSTM: SEQ=512, BATCH=32, IN=HID=1024, LAYERS=4. Inputs fp32, OUTPUT FP32.
// out (float): [512*32*1024 h_seq(layer3)] ++ [4*32*1024 h_last] ++ [4*32*1024 c_last]
//
// Round-9: scan latency surgery #2.
//  - W_hh fragments hoisted to REGISTERS (128 VGPR/lane; we run 1 wave/SIMD so
//    512 are free): removes 128KB/step of LDS reads + 2.9e7 bank conflicts.
//    LDS is now just the 16KB reduce buffer.
//  - Symmetric wave-granular barrier: 512 slots, each wave releases its own
//    slot (waves 0-1: s_waitcnt vmcnt(0) + relaxed sc1 store — valid release
//    since ALL scan stores are sc1/L3-direct; waves 2-3 have no stores).
//    Every wave polls all 512 slots -> ONE L3 round trip, no go fanout, no
//    fences, one less __syncthreads. Phase D skipped on the final step.
//  - Gates for step s+1 prefetched right after the mid-step sync.
//  - tanhf -> exp-based fast tanh (saturation-correct).

#define SEQ    512
#define BATCH  32
#define HID    1024
#define G4     4096
#define LAYERS 4

typedef unsigned short u16;
typedef unsigned int u32;
typedef unsigned long long u64;
typedef __attribute__((ext_vector_type(8))) short bf8;   // 8 bf16 (4 VGPRs) MFMA frag
typedef __attribute__((ext_vector_type(4))) float f4;

__device__ __forceinline__ u16 f2bf(float f) {           // RNE fp32->bf16
  uint32_t u = __float_as_uint(f);
  u += 0x7FFFu + ((u >> 16) & 1u);
  return (u16)(u >> 16);
}
__device__ __forceinline__ float bf2f(u16 h) {
  return __uint_as_float(((uint32_t)h) << 16);
}
__device__ __forceinline__ float sigf(float x) { return 1.f / (1.f + __expf(-x)); }
__device__ __forceinline__ float tanhfast(float x) {
  return 1.f - 2.f / (1.f + __expf(2.f * x));            // exact at +-inf, ~1e-7 abs err
}

// 16B load as two relaxed agent-scope 8B atomics (sc1: bypass L2, read L3)
__device__ __forceinline__ bf8 ld_bf8_sc(const u16* p) {
  union { u64 q[2]; bf8 v; } u;
  const u64* qp = (const u64*)p;
  u.q[0] = __hip_atomic_load(qp,     __ATOMIC_RELAXED, __HIP_MEMORY_SCOPE_AGENT);
  u.q[1] = __hip_atomic_load(qp + 1, __ATOMIC_RELAXED, __HIP_MEMORY_SCOPE_AGENT);
  return u.v;
}

// ---------------- split fp32 -> (hi, lo) bf16 ----------------
__global__ void cvt_split_kernel(const float* __restrict__ in, u16* __restrict__ hi,
                                 u16* __restrict__ lo, int n4) {
  int i = blockIdx.x * 256 + threadIdx.x;
  if (i >= n4) return;
  float4 v = reinterpret_cast<const float4*>(in)[i];
  ushort4 h, l;
  h.x = f2bf(v.x); l.x = f2bf(v.x - bf2f(h.x));
  h.y = f2bf(v.y); l.y = f2bf(v.y - bf2f(h.y));
  h.z = f2bf(v.z); l.z = f2bf(v.z - bf2f(h.z));
  h.w = f2bf(v.w); l.w = f2bf(v.w - bf2f(h.w));
  reinterpret_cast<ushort4*>(hi)[i] = h;
  reinterpret_cast<ushort4*>(lo)[i] = l;
}

__global__ void bias_comb_kernel(const float* __restrict__ a, const float* __restrict__ b,
                                 float* __restrict__ o, int n) {
  int i = blockIdx.x * 256 + threadIdx.x;
  if (i < n) o[i] = a[i] + b[i];
}

// ---------------- input projection GEMM, bf16x3 (unchanged, passing) ----------------
__launch_bounds__(256)
__global__ void gemm_xproj(const u16* __restrict__ Ah, const u16* __restrict__ Al,
                           const u16* __restrict__ Bh, const u16* __restrict__ Bl,
                           const float* __restrict__ bias, float* __restrict__ C) {
  __shared__ u16 Ash[128 * 32];
  __shared__ u16 Asl[128 * 32];
  __shared__ u16 Bsh[128 * 32];
  __shared__ u16 Bsl[128 * 32];
  const int tid  = threadIdx.x;
  const int lane = tid & 63;
  const int w    = tid >> 6;
  const int wm   = (w >> 1) * 64, wn = (w & 1) * 64;
  const int m0   = blockIdx.x * 128, n0 = blockIdx.y * 128;
  const int fr   = lane & 15;
  const int fk   = (lane >> 4) * 8;
  const f4 fz = {0.f, 0.f, 0.f, 0.f};
  f4 acc[4][4];
#pragma unroll
  for (int i = 0; i < 4; ++i)
#pragma unroll
    for (int j = 0; j < 4; ++j) acc[i][j] = fz;

  for (int kt = 0; kt < 1024; kt += 32) {
    __syncthreads();
#pragma unroll
    for (int i = 0; i < 2; ++i) {
      const int e   = (i * 256 + tid) * 8;
      const int row = e >> 5, kc = e & 31;
      const int ldsbase = (i * 256 + (tid & 192)) * 8;
      const size_t goffA = (size_t)(m0 + row) * 1024 + kt + kc;
      const size_t goffB = (size_t)(n0 + row) * 1024 + kt + kc;
      __builtin_amdgcn_global_load_lds(
          (const __attribute__((address_space(1))) void*)(Ah + goffA),
          (__attribute__((address_space(3))) void*)(Ash + ldsbase), 16, 0, 0);
      __builtin_amdgcn_global_load_lds(
          (const __attribute__((address_space(1))) void*)(Al + goffA),
          (__attribute__((address_space(3))) void*)(Asl + ldsbase), 16, 0, 0);
      __builtin_amdgcn_global_load_lds(
          (const __attribute__((address_space(1))) void*)(Bh + goffB),
          (__attribute__((address_space(3))) void*)(Bsh + ldsbase), 16, 0, 0);
      __builtin_amdgcn_global_load_lds(
          (const __attribute__((address_space(1))) void*)(Bl + goffB),
          (__attribute__((address_space(3))) void*)(Bsl + ldsbase), 16, 0, 0);
    }
    __syncthreads();
    bf8 ah[4], al[4], bh[4], bl[4];
#pragma unroll
    for (int f = 0; f < 4; ++f) {
      ah[f] = *reinterpret_cast<const bf8*>(Ash + (wm + f * 16 + fr) * 32 + fk);
      al[f] = *reinterpret_cast<const bf8*>(Asl + (wm + f * 16 + fr) * 32 + fk);
      bh[f] = *reinterpret_cast<const bf8*>(Bsh + (wn + f * 16 + fr) * 32 + fk);
      bl[f] = *reinterpret_cast<const bf8*>(Bsl + (wn + f * 16 + fr) * 32 + fk);
    }
#pragma unroll
    for (int i = 0; i < 4; ++i)
#pragma unroll
      for (int j = 0; j < 4; ++j) {
        acc[i][j] = __builtin_amdgcn_mfma_f32_16x16x32_bf16(ah[i], bh[j], acc[i][j], 0, 0, 0);
        acc[i][j] = __builtin_amdgcn_mfma_f32_16x16x32_bf16(ah[i], bl[j], acc[i][j], 0, 0, 0);
        acc[i][j] = __builtin_amdgcn_mfma_f32_16x16x32_bf16(al[i], bh[j], acc[i][j], 0, 0, 0);
      }
  }
  const int cr0 = (lane >> 4) * 4;
#pragma unroll
  for (int i = 0; i < 4; ++i)
#pragma unroll
    for (int j = 0; j < 4; ++j)
#pragma unroll
      for (int q = 0; q < 4; ++q) {
        const int rr = m0 + wm + i * 16 + cr0 + q;
        const int cc = n0 + wn + j * 16 + fr;
        C[(size_t)rr * 4096 + cc] = acc[i][j][q] + bias[cc];
      }
}

// ---------------- persistent recurrence scan (bf16x3, 128 blocks, W in VGPRs) --------
// block ug owns 8 hidden units (32 gate rows: g*1024 + ug*8 + uu). Each lane
// holds its 32 W fragments (512B = 128 VGPR) in registers for the whole
// dispatch. h ping-pong in global, layout [par][term][ktile=128][b=32][8] u16,
// all h accesses relaxed agent atomics (sc1 -> L3). LDS = 16KB reduce only.
// Barrier: wave-granular slots[512], manual vmcnt-release, symmetric poll.
#define HPP_Q 32768                             // u16 elems per (parity,term) plane

__launch_bounds__(256, 1)
__global__ void lstm_scan(const float* __restrict__ gates,   // [nsteps*32][4096] fp32
                          const u16* __restrict__ Whh_hi,    // [4096][1024] bf16
                          const u16* __restrict__ Whh_lo,
                          u16* __restrict__ h_pp,            // [2][2][128][32][8] u16
                          float* __restrict__ c_glob,        // [32][1024] fp32
                          float* __restrict__ hseq_f,        // [(t*32+b)*1024+u] fp32 (d_out)
                          float* __restrict__ hs_out,        // [b*1024+u] fp32
                          float* __restrict__ cs_out,        // [b*1024+u] fp32
                          int* __restrict__ slots,           // [512] one per wave
                          int t0, int tag0, int nsteps, int is_last) {
  __shared__ float red[4096];                   // [4 khq][2 mt][32 n][16 m]

  const int bid = blockIdx.x;      // = ug, 0..127
  const int ug  = bid;
  const int tid = threadIdx.x, lane = tid & 63, w = tid >> 6;

  const int fr = lane & 15, q4 = lane >> 4;
  const int khq = w;                             // K-quarter 0..3
  const int bcol0 = khq * 256 + q4 * 8;          // W col base (elems)

  // ---- preload this lane's 32 W fragments into registers (once) ----
  // local row n -> global gate row (n>>3)*1024 + ug*8 + (n&7); n = fr / 16+fr
  bf8 wh0[8], wl0[8], wh1[8], wl1[8];
  {
    const size_t grow0 = (size_t)((fr >> 3) * 1024 + ug * 8 + (fr & 7));
    const size_t grow1 = grow0 + 2048;          // (16+fr)>>3 = 2 + (fr>>3)
    const u16* bh0 = Whh_hi + grow0 * 1024 + bcol0;
    const u16* bl0 = Whh_lo + grow0 * 1024 + bcol0;
    const u16* bh1 = Whh_hi + grow1 * 1024 + bcol0;
    const u16* bl1 = Whh_lo + grow1 * 1024 + bcol0;
#pragma unroll
    for (int i = 0; i < 8; ++i) {
      wh0[i] = *reinterpret_cast<const bf8*>(bh0 + 32 * i);
      wl0[i] = *reinterpret_cast<const bf8*>(bl0 + 32 * i);
      wh1[i] = *reinterpret_cast<const bf8*>(bh1 + 32 * i);
      wl1[i] = *reinterpret_cast<const bf8*>(bl1 + 32 * i);
    }
  }

  float c0 = 0.f, c1 = 0.f;
  int b = 0, up = 0, u0 = 0;
  float2 gp0, gp1, gp2, gp3;
  if (tid < 128) {
    b = tid >> 2; up = tid & 3;                  // 32 batches x 4 unit-pairs
    u0 = ug * 8 + up * 2;                        // global unit (even)
    c0 = c_glob[b * 1024 + u0];
    c1 = c_glob[b * 1024 + u0 + 1];
    const float* gr = gates + (size_t)b * 4096 + u0;   // s = 0
    gp0 = *(const float2*)(gr);
    gp1 = *(const float2*)(gr + 1024);
    gp2 = *(const float2*)(gr + 2048);
    gp3 = *(const float2*)(gr + 3072);
  }

  const int aeo0 = fr * 8;                       // A elem offset, mt=0
  const int aeo1 = (16 + fr) * 8;                // mt=1
  const f4 fz = {0.f, 0.f, 0.f, 0.f};

  for (int s = 0; s < nsteps; ++s) {
    const int t = t0 + s;
    // phase B: matvec partials; h via sc1 atomics, W from registers
    {
      const u16* hh = h_pp + (size_t)((t & 1) * 2 + 0) * HPP_Q;
      const u16* hl = h_pp + (size_t)((t & 1) * 2 + 1) * HPP_Q;
      f4 a00 = fz, a01 = fz, a10 = fz, a11 = fz;   // [mt][nt]
#pragma unroll
      for (int i = 0; i < 8; ++i) {
        const int ab = (khq * 32 + 4 * i + q4) * 256;
        bf8 avh0 = ld_bf8_sc(hh + ab + aeo0);
        bf8 avl0 = ld_bf8_sc(hl + ab + aeo0);
        bf8 avh1 = ld_bf8_sc(hh + ab + aeo1);
        bf8 avl1 = ld_bf8_sc(hl + ab + aeo1);
        a00 = __builtin_amdgcn_mfma_f32_16x16x32_bf16(avh0, wh0[i], a00, 0, 0, 0);
        a00 = __builtin_amdgcn_mfma_f32_16x16x32_bf16(avh0, wl0[i], a00, 0, 0, 0);
        a00 = __builtin_amdgcn_mfma_f32_16x16x32_bf16(avl0, wh0[i], a00, 0, 0, 0);
        a01 = __builtin_amdgcn_mfma_f32_16x16x32_bf16(avh0, wh1[i], a01, 0, 0, 0);
        a01 = __builtin_amdgcn_mfma_f32_16x16x32_bf16(avh0, wl1[i], a01, 0, 0, 0);
        a01 = __builtin_amdgcn_mfma_f32_16x16x32_bf16(avl0, wh1[i], a01, 0, 0, 0);
        a10 = __builtin_amdgcn_mfma_f32_16x16x32_bf16(avh1, wh0[i], a10, 0, 0, 0);
        a10 = __builtin_amdgcn_mfma_f32_16x16x32_bf16(avh1, wl0[i], a10, 0, 0, 0);
        a10 = __builtin_amdgcn_mfma_f32_16x16x32_bf16(avl1, wh0[i], a10, 0, 0, 0);
        a11 = __builtin_amdgcn_mfma_f32_16x16x32_bf16(avh1, wh1[i], a11, 0, 0, 0);
        a11 = __builtin_amdgcn_mfma_f32_16x16x32_bf16(avh1, wl1[i], a11, 0, 0, 0);
        a11 = __builtin_amdgcn_mfma_f32_16x16x32_bf16(avl1, wh1[i], a11, 0, 0, 0);
      }
      float* r00 = red + (khq * 2 + 0) * 512 + fr * 16 + q4 * 4;
      float* r01 = r00 + 256;
      float* r10 = red + (khq * 2 + 1) * 512 + fr * 16 + q4 * 4;
      float* r11 = r10 + 256;
#pragma unroll
      for (int q = 0; q < 4; ++q) {
        r00[q] = a00[q]; r01[q] = a01[q]; r10[q] = a10[q]; r11[q] = a11[q];
      }
    }
    __syncthreads();
    // phase C: 128 threads = 32 batches x 4 unit-pairs; 2 cell updates each
    if (tid < 128) {
      // prefetch next step's gate slice first (hides under transcendentals)
      float2 gn0, gn1, gn2, gn3;
      {
        const int sp = (s + 1 < nsteps) ? s + 1 : s;
        const float* gr = gates + (size_t)(sp * 32 + b) * 4096 + u0;
        gn0 = *(const float2*)(gr);
        gn1 = *(const float2*)(gr + 1024);
        gn2 = *(const float2*)(gr + 2048);
        gn3 = *(const float2*)(gr + 3072);
      }
      const int bl = b & 15, bmt = b >> 4;
      float g00, g01, g02, g03, g10, g11, g12, g13;
      {
        const int nb0 = (up * 2) * 16 + bl;          // n = gg*8 + up*2 (+j)
        float s0, s1, s2, s3;
#pragma unroll
        for (int j = 0; j < 2; ++j) {
          const int nb = nb0 + j * 16;
          s0 = s1 = s2 = s3 = 0.f;
#pragma unroll
          for (int kq = 0; kq < 4; ++kq) {
            const float* rb = red + (kq * 2 + bmt) * 512 + nb;
            s0 += rb[0 * 128];
            s1 += rb[1 * 128];
            s2 += rb[2 * 128];
            s3 += rb[3 * 128];
          }
          if (j == 0) { g00 = s0 + gp0.x; g01 = s1 + gp1.x; g02 = s2 + gp2.x; g03 = s3 + gp3.x; }
          else        { g10 = s0 + gp0.y; g11 = s1 + gp1.y; g12 = s2 + gp2.y; g13 = s3 + gp3.y; }
        }
      }
      const float i0 = sigf(g00), f0 = sigf(g01), z0 = tanhfast(g02), o0 = sigf(g03);
      c0 = f0 * c0 + i0 * z0;
      const float h0 = o0 * tanhfast(c0);
      const float i1 = sigf(g10), f1 = sigf(g11), z1 = tanhfast(g12), o1 = sigf(g13);
      c1 = f1 * c1 + i1 * z1;
      const float h1 = o1 * tanhfast(c1);
      // hseq (fp32 pair, sc1)
      const u64 hv = ((u64)__float_as_uint(h1) << 32) | (u64)__float_as_uint(h0);
      __hip_atomic_store((u64*)(hseq_f + ((size_t)t * 32 + b) * 1024 + u0), hv,
                         __ATOMIC_RELAXED, __HIP_MEMORY_SCOPE_AGENT);
      // h ping-pong (hi/lo planes, packed u32 pairs, sc1)
      const u16 h0h = f2bf(h0), h0l = f2bf(h0 - bf2f(h0h));
      const u16 h1h = f2bf(h1), h1l = f2bf(h1 - bf2f(h1h));
      const int par2 = ((t + 1) & 1) * 2;
      const int tix  = ug * 256 + b * 8 + up * 2;       // u16 idx in plane
      __hip_atomic_store((u32*)(h_pp + (size_t)par2 * HPP_Q + tix),
                         (u32)h0h | ((u32)h1h << 16),
                         __ATOMIC_RELAXED, __HIP_MEMORY_SCOPE_AGENT);
      __hip_atomic_store((u32*)(h_pp + (size_t)(par2 + 1) * HPP_Q + tix),
                         (u32)h0l | ((u32)h1l << 16),
                         __ATOMIC_RELAXED, __HIP_MEMORY_SCOPE_AGENT);
      if (is_last && s == nsteps - 1) {
        hs_out[b * 1024 + u0]     = h0;
        hs_out[b * 1024 + u0 + 1] = h1;
        cs_out[b * 1024 + u0]     = c0;
        cs_out[b * 1024 + u0 + 1] = c1;
      }
      gp0 = gn0; gp1 = gn1; gp2 = gn2; gp3 = gn3;       // rotate prefetch
    }
    // phase D: symmetric wave-granular barrier (skipped after final step).
    //  waves 0-1: vmcnt(0) drains their sc1 stores (acked at L3 = coherence
    //  point) THEN the slot store -> valid release without wbl2/fences.
    //  waves 2-3 have no stores. All waves poll all 512 slots (relaxed, sc1).
    if (s + 1 < nsteps) {
      const int tag = tag0 + s + 1;
      if (w < 2) asm volatile("s_waitcnt vmcnt(0)" ::: "memory");
      if (lane == 0)
        __hip_atomic_store(slots + bid * 4 + w, tag, __ATOMIC_RELAXED, __HIP_MEMORY_SCOPE_AGENT);
      const u64* sl64 = (const u64*)slots;
      for (;;) {
        u64 v0 = __hip_atomic_load(sl64 + lane * 4 + 0, __ATOMIC_RELAXED, __HIP_MEMORY_SCOPE_AGENT);
        u64 v1 = __hip_atomic_load(sl64 + lane * 4 + 1, __ATOMIC_RELAXED, __HIP_MEMORY_SCOPE_AGENT);
        u64 v2 = __hip_atomic_load(sl64 + lane * 4 + 2, __ATOMIC_RELAXED, __HIP_MEMORY_SCOPE_AGENT);
        u64 v3 = __hip_atomic_load(sl64 + lane * 4 + 3, __ATOMIC_RELAXED, __HIP_MEMORY_SCOPE_AGENT);
        bool ok = ((int)v0 >= tag) && ((int)(v0 >> 32) >= tag)
               && ((int)v1 >= tag) && ((int)(v1 >> 32) >= tag)
               && ((int)v2 >= tag) && ((int)(v2 >> 32) >= tag)
               && ((int)v3 >= tag) && ((int)(v3 >> 32) >= tag);
        if (__all(ok)) break;
        __builtin_amdgcn_s_sleep(1);
      }
      __builtin_amdgcn_sched_barrier(0);   // keep next-step h loads below the poll
    }
  }
  if (tid < 128) {
    c_glob[b * 1024 + u0]     = c0;
    c_glob[b * 1024 + u0 + 1] = c1;
  }
}

// ---------------- host launcher ----------------
extern "C" void kernel_launch(void* const* d_in, const int* in_sizes, int n_in,
                              void* d_out, int out_size, void* d_ws, size_t ws_size,
                              hipStream_t stream) {
  const float* x   = (const float*)d_in[0];
  const float* Wih = (const float*)d_in[1];
  const float* Whh = (const float*)d_in[2];
  const float* bih = (const float*)d_in[3];
  const float* bhh = (const float*)d_in[4];
  float* out = (float*)d_out;                         // FP32 output buffer

  float* outh = out;                                  // h_seq region = inter-layer fp32 acts
  const size_t OFF1 = (size_t)SEQ * BATCH * HID;      // 16777216
  const size_t OFF2 = OFF1 + (size_t)LAYERS * BATCH * HID;

  // workspace layout
  char* ws = (char*)d_ws;
  u16*   wih_hi = (u16*)ws;                                  // 8MB (per-layer)
  u16*   wih_lo = (u16*)(ws + (8ull  << 20));                // 8MB
  u16*   whh_hi = (u16*)(ws + (16ull << 20));                // 8MB
  u16*   whh_lo = (u16*)(ws + (24ull << 20));                // 8MB
  float* biasc  = (float*)(ws + (32ull << 20));              // 64KB (all layers)
  u16*   h_pp   = (u16*)(ws + (32ull << 20) + (64ull << 10));        // 256KB
  float* c_glob = (float*)(ws + (32ull << 20) + (320ull << 10));     // 128KB
  int*   bar    = (int*)(ws + (32ull << 20) + (448ull << 10));       // 4KB: slots[512]
  char*  dynws  = ws + (33ull << 20);

  // chunk T: 33MB + T*(64KB xh + 64KB xl + 512KB gates) <= ws_size
  int T = 128;
  while (T > 8 && (33ull << 20) + (size_t)T * (640ull << 10) > ws_size) T >>= 1;
  const int nchunk = SEQ / T;
  u16*   xb_hi = (u16*)dynws;                                          // T*32*1024
  u16*   xb_lo = (u16*)(dynws + (size_t)T * BATCH * HID * sizeof(u16));
  float* gates = (float*)(dynws + (size_t)2 * T * BATCH * HID * sizeof(u16));

  hipMemsetAsync(bar, 0, 4096, stream);
  bias_comb_kernel<<<(LAYERS * G4 + 255) / 256, 256, 0, stream>>>(bih, bhh, biasc, LAYERS * G4);

  int tag0 = 0;
  for (int l = 0; l < LAYERS; ++l) {
    cvt_split_kernel<<<G4 * HID / 4 / 256, 256, 0, stream>>>(
        Wih + (size_t)l * G4 * HID, wih_hi, wih_lo, G4 * HID / 4);
    cvt_split_kernel<<<G4 * HID / 4 / 256, 256, 0, stream>>>(
        Whh + (size_t)l * G4 * HID, whh_hi, whh_lo, G4 * HID / 4);
    hipMemsetAsync(h_pp, 0, 4 * HPP_Q * sizeof(u16), stream);
    hipMemsetAsync(c_glob, 0, BATCH * HID * sizeof(float), stream);
    for (int cch = 0; cch < nchunk; ++cch) {
      const float* asrc = (l == 0) ? (x + (size_t)cch * T * BATCH * HID)
                                   : (outh + (size_t)cch * T * BATCH * HID);
      cvt_split_kernel<<<T * BATCH * HID / 4 / 256, 256, 0, stream>>>(
          asrc, xb_hi, xb_lo, T * BATCH * HID / 4);
      gemm_xproj<<<dim3(T * BATCH / 128, 32), 256, 0, stream>>>(
          xb_hi, xb_lo, wih_hi, wih_lo, biasc + l * G4, gates);
      lstm_scan<<<128, 256, 0, stream>>>(
          gates, whh_hi, whh_lo, h_pp, c_glob,
          outh,
          out + OFF1 + (size_t)l * BATCH * HID,
          out + OFF2 + (size_t)l * BATCH * HID,
          bar,
          cch * T, tag0, T, (cch == nchunk - 1) ? 1 : 0);
      tag0 += T;
    }
  }
  (void)in_sizes; (void)n_in; (void)out_size;
}

// Round 11
// 13743.919 us; speedup vs baseline: 1.6584x; 1.6584x over previous
//
#include <hip/hip_runtime.h>
#include <stdint.h>

// LSTM: SEQ=512, BATCH=32, IN=HID=1024, LAYERS=4. Inputs fp32, OUTPUT FP32.
// out (float): [512*32*1024 h_seq(layer3)] ++ [4*32*1024 h_last] ++ [4*32*1024 c_last]
//
// Round-10: revert round-9's failed W-in-VGPR (compiler scratch-spilled it:
// VGPR_Count=120 < the 128 needed; scratch reads regressed 60%) back to the
// round-8 W-in-LDS structure, then replace the 2-hop centralized barrier
// (slots -> block0 aggregate -> fence -> go fanout -> waiter poll) with a
// DATAFLOW producer poll: h ktile k is produced exactly by block k, so each
// lane polls its 8 producer slots directly (relaxed sc1), and each block
// publishes its slot right after its h stores drain. Removes ~3 serial L3
// round trips per step. Publishes happen EVERY step (incl. last) so
// consecutive dispatches chain: first poll of a dispatch = tag0 = previous
// dispatch's final publish (memset-0 bootstraps the first).
//  + WLD 1032->1036 (spreads W ds_read_b128 bank starts), fast tanh.

#define SEQ    512
#define BATCH  32
#define HID    1024
#define G4     4096
#define LAYERS 4

typedef unsigned short u16;
typedef unsigned int u32;
typedef unsigned long long u64;
typedef __attribute__((ext_vector_type(8))) short bf8;   // 8 bf16 (4 VGPRs) MFMA frag
typedef __attribute__((ext_vector_type(4))) float f4;

__device__ __forceinline__ u16 f2bf(float f) {           // RNE fp32->bf16
  uint32_t u = __float_as_uint(f);
  u += 0x7FFFu + ((u >> 16) & 1u);
  return (u16)(u >> 16);
}
__device__ __forceinline__ float bf2f(u16 h) {
  return __uint_as_float(((uint32_t)h) << 16);
}
__device__ __forceinline__ float sigf(float x) { return 1.f / (1.f + __expf(-x)); }
__device__ __forceinline__ float tanhfast(float x) {
  return 1.f - 2.f / (1.f + __expf(2.f * x));            // exact at +-inf
}

// 16B load as two relaxed agent-scope 8B atomics (sc1: bypass L2, read L3)
__device__ __forceinline__ bf8 ld_bf8_sc(const u16* p) {
  union { u64 q[2]; bf8 v; } u;
  const u64* qp = (const u64*)p;
  u.q[0] = __hip_atomic_load(qp,     __ATOMIC_RELAXED, __HIP_MEMORY_SCOPE_AGENT);
  u.q[1] = __hip_atomic_load(qp + 1, __ATOMIC_RELAXED, __HIP_MEMORY_SCOPE_AGENT);
  return u.v;
}

// ---------------- split fp32 -> (hi, lo) bf16 ----------------
__global__ void cvt_split_kernel(const float* __restrict__ in, u16* __restrict__ hi,
                                 u16* __restrict__ lo, int n4) {
  int i = blockIdx.x * 256 + threadIdx.x;
  if (i >= n4) return;
  float4 v = reinterpret_cast<const float4*>(in)[i];
  ushort4 h, l;
  h.x = f2bf(v.x); l.x = f2bf(v.x - bf2f(h.x));
  h.y = f2bf(v.y); l.y = f2bf(v.y - bf2f(h.y));
  h.z = f2bf(v.z); l.z = f2bf(v.z - bf2f(h.z));
  h.w = f2bf(v.w); l.w = f2bf(v.w - bf2f(h.w));
  reinterpret_cast<ushort4*>(hi)[i] = h;
  reinterpret_cast<ushort4*>(lo)[i] = l;
}

__global__ void bias_comb_kernel(const float* __restrict__ a, const float* __restrict__ b,
                                 float* __restrict__ o, int n) {
  int i = blockIdx.x * 256 + threadIdx.x;
  if (i < n) o[i] = a[i] + b[i];
}

// ---------------- input projection GEMM, bf16x3 (unchanged, passing) ----------------
__launch_bounds__(256)
__global__ void gemm_xproj(const u16* __restrict__ Ah, const u16* __restrict__ Al,
                           const u16* __restrict__ Bh, const u16* __restrict__ Bl,
                           const float* __restrict__ bias, float* __restrict__ C) {
  __shared__ u16 Ash[128 * 32];
  __shared__ u16 Asl[128 * 32];
  __shared__ u16 Bsh[128 * 32];
  __shared__ u16 Bsl[128 * 32];
  const int tid  = threadIdx.x;
  const int lane = tid & 63;
  const int w    = tid >> 6;
  const int wm   = (w >> 1) * 64, wn = (w & 1) * 64;
  const int m0   = blockIdx.x * 128, n0 = blockIdx.y * 128;
  const int fr   = lane & 15;
  const int fk   = (lane >> 4) * 8;
  const f4 fz = {0.f, 0.f, 0.f, 0.f};
  f4 acc[4][4];
#pragma unroll
  for (int i = 0; i < 4; ++i)
#pragma unroll
    for (int j = 0; j < 4; ++j) acc[i][j] = fz;

  for (int kt = 0; kt < 1024; kt += 32) {
    __syncthreads();
#pragma unroll
    for (int i = 0; i < 2; ++i) {
      const int e   = (i * 256 + tid) * 8;
      const int row = e >> 5, kc = e & 31;
      const int ldsbase = (i * 256 + (tid & 192)) * 8;
      const size_t goffA = (size_t)(m0 + row) * 1024 + kt + kc;
      const size_t goffB = (size_t)(n0 + row) * 1024 + kt + kc;
      __builtin_amdgcn_global_load_lds(
          (const __attribute__((address_space(1))) void*)(Ah + goffA),
          (__attribute__((address_space(3))) void*)(Ash + ldsbase), 16, 0, 0);
      __builtin_amdgcn_global_load_lds(
          (const __attribute__((address_space(1))) void*)(Al + goffA),
          (__attribute__((address_space(3))) void*)(Asl + ldsbase), 16, 0, 0);
      __builtin_amdgcn_global_load_lds(
          (const __attribute__((address_space(1))) void*)(Bh + goffB),
          (__attribute__((address_space(3))) void*)(Bsh + ldsbase), 16, 0, 0);
      __builtin_amdgcn_global_load_lds(
          (const __attribute__((address_space(1))) void*)(Bl + goffB),
          (__attribute__((address_space(3))) void*)(Bsl + ldsbase), 16, 0, 0);
    }
    __syncthreads();
    bf8 ah[4], al[4], bh[4], bl[4];
#pragma unroll
    for (int f = 0; f < 4; ++f) {
      ah[f] = *reinterpret_cast<const bf8*>(Ash + (wm + f * 16 + fr) * 32 + fk);
      al[f] = *reinterpret_cast<const bf8*>(Asl + (wm + f * 16 + fr) * 32 + fk);
      bh[f] = *reinterpret_cast<const bf8*>(Bsh + (wn + f * 16 + fr) * 32 + fk);
      bl[f] = *reinterpret_cast<const bf8*>(Bsl + (wn + f * 16 + fr) * 32 + fk);
    }
#pragma unroll
    for (int i = 0; i < 4; ++i)
#pragma unroll
      for (int j = 0; j < 4; ++j) {
        acc[i][j] = __builtin_amdgcn_mfma_f32_16x16x32_bf16(ah[i], bh[j], acc[i][j], 0, 0, 0);
        acc[i][j] = __builtin_amdgcn_mfma_f32_16x16x32_bf16(ah[i], bl[j], acc[i][j], 0, 0, 0);
        acc[i][j] = __builtin_amdgcn_mfma_f32_16x16x32_bf16(al[i], bh[j], acc[i][j], 0, 0, 0);
      }
  }
  const int cr0 = (lane >> 4) * 4;
#pragma unroll
  for (int i = 0; i < 4; ++i)
#pragma unroll
    for (int j = 0; j < 4; ++j)
#pragma unroll
      for (int q = 0; q < 4; ++q) {
        const int rr = m0 + wm + i * 16 + cr0 + q;
        const int cc = n0 + wn + j * 16 + fr;
        C[(size_t)rr * 4096 + cc] = acc[i][j][q] + bias[cc];
      }
}

// ---------------- persistent recurrence scan (bf16x3, 128 blocks, dataflow sync) ------
// block ug owns 8 hidden units (32 gate rows: g*1024 + ug*8 + uu). W rows hi+lo
// LDS-resident. h ping-pong [par][term][ktile=128][b=32][8] u16 via relaxed sc1
// atomics. ktile k is produced by block k => per-step sync = per-lane poll of
// its 8 producer slots (spread 1/64B line), publish after own h stores drain.
#define WLD   1036                              // padded W row stride (bf16 elems)
#define HPP_Q 32768                             // u16 elems per (parity,term) plane
#define WBYTES (32 * WLD * 2)                   // 66304
#define SSMEM (2 * WBYTES + 16384)              // Wh + Wl + red = 148992 B

__launch_bounds__(256, 1)
__global__ void lstm_scan(const float* __restrict__ gates,   // [nsteps*32][4096] fp32
                          const u16* __restrict__ Whh_hi,    // [4096][1024] bf16
                          const u16* __restrict__ Whh_lo,
                          u16* __restrict__ h_pp,            // [2][2][128][32][8] u16
                          float* __restrict__ c_glob,        // [32][1024] fp32
                          float* __restrict__ hseq_f,        // [(t*32+b)*1024+u] fp32 (d_out)
                          float* __restrict__ hs_out,        // [b*1024+u] fp32
                          float* __restrict__ cs_out,        // [b*1024+u] fp32
                          int* __restrict__ slots,           // [128*16] 1 slot per 64B line
                          int t0, int tag0, int nsteps, int is_last) {
  extern __shared__ char smem[];
  u16*   Wh  = (u16*)smem;                       // [32][WLD]
  u16*   Wl  = (u16*)(smem + WBYTES);            // [32][WLD]
  float* red = (float*)(smem + 2 * WBYTES);      // [4 khq][2 mt][32 n][16 m]

  const int bid = blockIdx.x;      // = ug, 0..127
  const int ug  = bid;
  const int tid = threadIdx.x, lane = tid & 63, w = tid >> 6;

  // stage 32 W rows (hi+lo): local row n -> global gate row (n>>3)*1024 + ug*8 + (n&7)
  {
    const int n  = tid & 31;
    const int ch = tid >> 5;                     // 8 column chunks of 128
    const size_t grow = (size_t)((n >> 3) * 1024 + ug * 8 + (n & 7));
    const u16* sh = Whh_hi + grow * 1024 + ch * 128;
    const u16* sl = Whh_lo + grow * 1024 + ch * 128;
    u16* dh = Wh + n * WLD + ch * 128;
    u16* dl = Wl + n * WLD + ch * 128;
#pragma unroll
    for (int it = 0; it < 16; ++it) {
      *reinterpret_cast<bf8*>(dh + it * 8) = *reinterpret_cast<const bf8*>(sh + it * 8);
      *reinterpret_cast<bf8*>(dl + it * 8) = *reinterpret_cast<const bf8*>(sl + it * 8);
    }
  }

  float c0 = 0.f, c1 = 0.f;
  int b = 0, up = 0, u0 = 0;
  if (tid < 128) {
    b = tid >> 2; up = tid & 3;                  // 32 batches x 4 unit-pairs
    u0 = ug * 8 + up * 2;                        // global unit (even)
    c0 = c_glob[b * 1024 + u0];
    c1 = c_glob[b * 1024 + u0 + 1];
  }
  __syncthreads();

  const int fr = lane & 15, q4 = lane >> 4;
  const int khq = w;                             // K-quarter 0..3
  const int aeo0 = fr * 8;                       // A elem offset, mt=0
  const int aeo1 = (16 + fr) * 8;                // mt=1
  const int brow0 = fr * WLD;                    // W row base, nt=0
  const int brow1 = (16 + fr) * WLD;             // nt=1
  const int bcol0 = khq * 256 + q4 * 8;          // W col base (elems)
  const int pbase = (khq * 32 + q4) * 16;        // producer slot base (+ i*64)
  const f4 fz = {0.f, 0.f, 0.f, 0.f};

  for (int s = 0; s < nsteps; ++s) {
    const int t = t0 + s;
    // gates prefetch (cached; overlaps the poll + h-load latency)
    float2 gp0, gp1, gp2, gp3;
    if (tid < 128) {
      const float* gr = gates + (size_t)(s * 32 + b) * 4096 + u0;
      gp0 = *(const float2*)(gr);
      gp1 = *(const float2*)(gr + 1024);
      gp2 = *(const float2*)(gr + 2048);
      gp3 = *(const float2*)(gr + 3072);
    }
    // dataflow gate: wait for this lane's 8 producer blocks to publish step s.
    // ktile(i) = khq*32 + 4i + q4 is produced by block of the same index.
    {
      const int tagS = tag0 + s;
      for (;;) {
        bool ok = true;
#pragma unroll
        for (int i = 0; i < 8; ++i) {
          int v = __hip_atomic_load(slots + pbase + i * 64,
                                    __ATOMIC_RELAXED, __HIP_MEMORY_SCOPE_AGENT);
          ok &= (v >= tagS);
        }
        if (ok) break;
        __builtin_amdgcn_s_sleep(1);
      }
      __builtin_amdgcn_sched_barrier(0);   // h loads must not hoist above the poll
    }
    // phase B: matvec partials; h via sc1 atomics, W from LDS
    {
      const u16* hh = h_pp + (size_t)((t & 1) * 2 + 0) * HPP_Q;
      const u16* hl = h_pp + (size_t)((t & 1) * 2 + 1) * HPP_Q;
      f4 a00 = fz, a01 = fz, a10 = fz, a11 = fz;   // [mt][nt]
#pragma unroll
      for (int kc8 = 0; kc8 < 32; kc8 += 4) {
        const int ab = (khq * 32 + kc8 + q4) * 256;
        bf8 avh0 = ld_bf8_sc(hh + ab + aeo0);
        bf8 avl0 = ld_bf8_sc(hl + ab + aeo0);
        bf8 avh1 = ld_bf8_sc(hh + ab + aeo1);
        bf8 avl1 = ld_bf8_sc(hl + ab + aeo1);
        const int bc = bcol0 + kc8 * 8;
        bf8 bvh0 = *reinterpret_cast<const bf8*>(Wh + brow0 + bc);
        bf8 bvl0 = *reinterpret_cast<const bf8*>(Wl + brow0 + bc);
        bf8 bvh1 = *reinterpret_cast<const bf8*>(Wh + brow1 + bc);
        bf8 bvl1 = *reinterpret_cast<const bf8*>(Wl + brow1 + bc);
        a00 = __builtin_amdgcn_mfma_f32_16x16x32_bf16(avh0, bvh0, a00, 0, 0, 0);
        a00 = __builtin_amdgcn_mfma_f32_16x16x32_bf16(avh0, bvl0, a00, 0, 0, 0);
        a00 = __builtin_amdgcn_mfma_f32_16x16x32_bf16(avl0, bvh0, a00, 0, 0, 0);
        a01 = __builtin_amdgcn_mfma_f32_16x16x32_bf16(avh0, bvh1, a01, 0, 0, 0);
        a01 = __builtin_amdgcn_mfma_f32_16x16x32_bf16(avh0, bvl1, a01, 0, 0, 0);
        a01 = __builtin_amdgcn_mfma_f32_16x16x32_bf16(avl0, bvh1, a01, 0, 0, 0);
        a10 = __builtin_amdgcn_mfma_f32_16x16x32_bf16(avh1, bvh0, a10, 0, 0, 0);
        a10 = __builtin_amdgcn_mfma_f32_16x16x32_bf16(avh1, bvl0, a10, 0, 0, 0);
        a10 = __builtin_amdgcn_mfma_f32_16x16x32_bf16(avl1, bvh0, a10, 0, 0, 0);
        a11 = __builtin_amdgcn_mfma_f32_16x16x32_bf16(avh1, bvh1, a11, 0, 0, 0);
        a11 = __builtin_amdgcn_mfma_f32_16x16x32_bf16(avh1, bvl1, a11, 0, 0, 0);
        a11 = __builtin_amdgcn_mfma_f32_16x16x32_bf16(avl1, bvh1, a11, 0, 0, 0);
      }
      float* r00 = red + (khq * 2 + 0) * 512 + fr * 16 + q4 * 4;
      float* r01 = r00 + 256;
      float* r10 = red + (khq * 2 + 1) * 512 + fr * 16 + q4 * 4;
      float* r11 = r10 + 256;
#pragma unroll
      for (int q = 0; q < 4; ++q) {
        r00[q] = a00[q]; r01[q] = a01[q]; r10[q] = a10[q]; r11[q] = a11[q];
      }
    }
    __syncthreads();
    // phase C: 128 threads = 32 batches x 4 unit-pairs; 2 cell updates each
    if (tid < 128) {
      const int bl = b & 15, bmt = b >> 4;
      float g00, g01, g02, g03, g10, g11, g12, g13;
      {
        const int nb0 = (up * 2) * 16 + bl;
        float s0, s1, s2, s3;
#pragma unroll
        for (int j = 0; j < 2; ++j) {
          const int nb = nb0 + j * 16;
          s0 = s1 = s2 = s3 = 0.f;
#pragma unroll
          for (int kq = 0; kq < 4; ++kq) {
            const float* rb = red + (kq * 2 + bmt) * 512 + nb;
            s0 += rb[0 * 128];
            s1 += rb[1 * 128];
            s2 += rb[2 * 128];
            s3 += rb[3 * 128];
          }
          if (j == 0) { g00 = s0 + gp0.x; g01 = s1 + gp1.x; g02 = s2 + gp2.x; g03 = s3 + gp3.x; }
          else        { g10 = s0 + gp0.y; g11 = s1 + gp1.y; g12 = s2 + gp2.y; g13 = s3 + gp3.y; }
        }
      }
      const float i0 = sigf(g00), f0 = sigf(g01), z0 = tanhfast(g02), o0 = sigf(g03);
      c0 = f0 * c0 + i0 * z0;
      const float h0 = o0 * tanhfast(c0);
      const float i1 = sigf(g10), f1 = sigf(g11), z1 = tanhfast(g12), o1 = sigf(g13);
      c1 = f1 * c1 + i1 * z1;
      const float h1 = o1 * tanhfast(c1);
      // hseq (fp32 pair, sc1)
      const u64 hv = ((u64)__float_as_uint(h1) << 32) | (u64)__float_as_uint(h0);
      __hip_atomic_store((u64*)(hseq_f + ((size_t)t * 32 + b) * 1024 + u0), hv,
                         __ATOMIC_RELAXED, __HIP_MEMORY_SCOPE_AGENT);
      // h ping-pong (hi/lo planes, packed u32 pairs, sc1)
      const u16 h0h = f2bf(h0), h0l = f2bf(h0 - bf2f(h0h));
      const u16 h1h = f2bf(h1), h1l = f2bf(h1 - bf2f(h1h));
      const int par2 = ((t + 1) & 1) * 2;
      const int tix  = ug * 256 + b * 8 + up * 2;       // u16 idx in plane
      __hip_atomic_store((u32*)(h_pp + (size_t)par2 * HPP_Q + tix),
                         (u32)h0h | ((u32)h1h << 16),
                         __ATOMIC_RELAXED, __HIP_MEMORY_SCOPE_AGENT);
      __hip_atomic_store((u32*)(h_pp + (size_t)(par2 + 1) * HPP_Q + tix),
                         (u32)h0l | ((u32)h1l << 16),
                         __ATOMIC_RELAXED, __HIP_MEMORY_SCOPE_AGENT);
      if (is_last && s == nsteps - 1) {
        hs_out[b * 1024 + u0]     = h0;
        hs_out[b * 1024 + u0 + 1] = h1;
        cs_out[b * 1024 + u0]     = c0;
        cs_out[b * 1024 + u0 + 1] = c1;
      }
    }
    // publish: __syncthreads drains all h stores (vmcnt0 -> acked at L3 for
    // sc1), then tid0's relaxed slot store becomes visible strictly after the
    // data. EVERY step publishes (chains chunks/layers: next dispatch polls
    // tag0' = this tag0 + nsteps).
    __syncthreads();
    if (tid == 0)
      __hip_atomic_store(slots + bid * 16, tag0 + s + 1,
                         __ATOMIC_RELAXED, __HIP_MEMORY_SCOPE_AGENT);
  }
  if (tid < 128) {
    c_glob[b * 1024 + u0]     = c0;
    c_glob[b * 1024 + u0 + 1] = c1;
  }
}

// ---------------- host launcher ----------------
extern "C" void kernel_launch(void* const* d_in, const int* in_sizes, int n_in,
                              void* d_out, int out_size, void* d_ws, size_t ws_size,
                              hipStream_t stream) {
  const float* x   = (const float*)d_in[0];
  const float* Wih = (const float*)d_in[1];
  const float* Whh = (const float*)d_in[2];
  const float* bih = (const float*)d_in[3];
  const float* bhh = (const float*)d_in[4];
  float* out = (float*)d_out;                         // FP32 output buffer

  float* outh = out;                                  // h_seq region = inter-layer fp32 acts
  const size_t OFF1 = (size_t)SEQ * BATCH * HID;      // 16777216
  const size_t OFF2 = OFF1 + (size_t)LAYERS * BATCH * HID;

  // workspace layout
  char* ws = (char*)d_ws;
  u16*   wih_hi = (u16*)ws;                                  // 8MB (per-layer)
  u16*   wih_lo = (u16*)(ws + (8ull  << 20));                // 8MB
  u16*   whh_hi = (u16*)(ws + (16ull << 20));                // 8MB
  u16*   whh_lo = (u16*)(ws + (24ull << 20));                // 8MB
  float* biasc  = (float*)(ws + (32ull << 20));              // 64KB (all layers)
  u16*   h_pp   = (u16*)(ws + (32ull << 20) + (64ull << 10));        // 256KB
  float* c_glob = (float*)(ws + (32ull << 20) + (320ull << 10));     // 128KB
  int*   bar    = (int*)(ws + (32ull << 20) + (448ull << 10));       // 8KB: slots[128*16]
  char*  dynws  = ws + (33ull << 20);

  // chunk T: 33MB + T*(64KB xh + 64KB xl + 512KB gates) <= ws_size
  int T = 128;
  while (T > 8 && (33ull << 20) + (size_t)T * (640ull << 10) > ws_size) T >>= 1;
  const int nchunk = SEQ / T;
  u16*   xb_hi = (u16*)dynws;                                          // T*32*1024
  u16*   xb_lo = (u16*)(dynws + (size_t)T * BATCH * HID * sizeof(u16));
  float* gates = (float*)(dynws + (size_t)2 * T * BATCH * HID * sizeof(u16));

  hipFuncSetAttribute(reinterpret_cast<const void*>(lstm_scan),
                      hipFuncAttributeMaxDynamicSharedMemorySize, SSMEM);

  hipMemsetAsync(bar, 0, 8192, stream);
  bias_comb_kernel<<<(LAYERS * G4 + 255) / 256, 256, 0, stream>>>(bih, bhh, biasc, LAYERS * G4);

  int tag0 = 0;
  for (int l = 0; l < LAYERS; ++l) {
    cvt_split_kernel<<<G4 * HID / 4 / 256, 256, 0, stream>>>(
        Wih + (size_t)l * G4 * HID, wih_hi, wih_lo, G4 * HID / 4);
    cvt_split_kernel<<<G4 * HID / 4 / 256, 256, 0, stream>>>(
        Whh + (size_t)l * G4 * HID, whh_hi, whh_lo, G4 * HID / 4);
    hipMemsetAsync(h_pp, 0, 4 * HPP_Q * sizeof(u16), stream);
    hipMemsetAsync(c_glob, 0, BATCH * HID * sizeof(float), stream);
    for (int cch = 0; cch < nchunk; ++cch) {
      const float* asrc = (l == 0) ? (x + (size_t)cch * T * BATCH * HID)
                                   : (outh + (size_t)cch * T * BATCH * HID);
      cvt_split_kernel<<<T * BATCH * HID / 4 / 256, 256, 0, stream>>>(
          asrc, xb_hi, xb_lo, T * BATCH * HID / 4);
      gemm_xproj<<<dim3(T * BATCH / 128, 32), 256, 0, stream>>>(
          xb_hi, xb_lo, wih_hi, wih_lo, biasc + l * G4, gates);
      lstm_scan<<<128, 256, SSMEM, stream>>>(
          gates, whh_hi, whh_lo, h_pp, c_glob,
          outh,
          out + OFF1 + (size_t)l * BATCH * HID,
          out + OFF2 + (size_t)l * BATCH * HID,
          bar,
          cch * T, tag0, T, (cch == nchunk - 1) ? 1 : 0);
      tag0 += T;
    }
  }
  (void)in_sizes; (void)n_in; (void)out_size;
}